// Round 1
// baseline (2989.156 us; speedup 1.0000x reference)
//
#include <hip/hip_runtime.h>
#include <cstddef>

#define Bn 4
#define Cn 256
#define Hn 100
#define Wn 100
#define HWn 10000
#define Kn 9

// ---------------------------------------------------------------------------
// Weight pre-transpose for deform GEMM: wt[br][k][c][o] = w_br[o][c][k]
// grid: 512 blocks x 256
// ---------------------------------------------------------------------------
__global__ __launch_bounds__(256) void wtrans_kernel(
    const float* __restrict__ wcls, const float* __restrict__ wreg,
    float* __restrict__ wt)
{
  int i = blockIdx.x * 256 + threadIdx.x;
  if (i >= 2 * Cn * Cn) return;
  int br  = i / (Cn * Cn);
  int rem = i - br * (Cn * Cn);
  int o = rem >> 8;      // 0..255
  int c = rem & 255;
  const float* src = (br ? wreg : wcls) + ((size_t)o * Cn + c) * Kn;
  float* dst = wt + (size_t)br * Kn * Cn * Cn + (size_t)c * Cn + o;
#pragma unroll
  for (int k = 0; k < Kn; ++k)
    dst[(size_t)k * Cn * Cn] = src[k];
}

// ---------------------------------------------------------------------------
// conv3x3 (pad 1) + bias + relu.  Tile: 128 co x (2 rows x 16 x).
// grid: (7 xtiles * 50 ytiles, 2 co-tiles, 4 b); block 256
// ---------------------------------------------------------------------------
__global__ __launch_bounds__(256) void conv3x3_relu_kernel(
    const float* __restrict__ in, const float* __restrict__ w,
    const float* __restrict__ bias, float* __restrict__ out)
{
  const int xt  = blockIdx.x % 7;
  const int yt  = blockIdx.x / 7;
  const int co0 = blockIdx.y * 128;
  const int b   = blockIdx.z;
  const int x0  = xt * 16;
  const int y0  = yt * 2;
  const int tid = threadIdx.x;
  const int cog = tid >> 3;        // 0..31 -> co = co0 + cog*4 + u
  const int xg  = tid & 7;
  const int row = xg >> 2;         // 0..1
  const int xs  = (xg & 3) * 4;    // 0,4,8,12

  __shared__ float wlds[8 * 9 * 132];   // [ci][tap][co pad132]
  __shared__ float ilds[8 * 4 * 20];    // [ci][4 rows][18 x pad20]

  float acc[4][4] = {};

  const float* inb = in + (size_t)b * Cn * HWn;

  for (int ci0 = 0; ci0 < Cn; ci0 += 8) {
    __syncthreads();
    // weights: per co, [ci0..ci0+8)x9 = 72 contiguous floats
    for (int i = tid; i < 128 * 72; i += 256) {
      int co = i / 72, j = i % 72;
      int ci = j / 9, tap = j % 9;
      wlds[(ci * 9 + tap) * 132 + co] =
          w[(size_t)(co0 + co) * (Cn * 9) + (size_t)ci0 * 9 + j];
    }
    // input halo tile: 8 ci x 4 rows x 18 x (zero-padded)
    for (int i = tid; i < 8 * 4 * 18; i += 256) {
      int ci = i / 72, r = i % 72;
      int rr = r / 18, xx = r % 18;
      int yy = y0 + rr - 1;
      int xi = x0 + xx - 1;
      float v = 0.f;
      if (yy >= 0 && yy < Hn && xi >= 0 && xi < Wn)
        v = inb[(size_t)(ci0 + ci) * HWn + yy * Wn + xi];
      ilds[(ci * 4 + rr) * 20 + xx] = v;
    }
    __syncthreads();
#pragma unroll
    for (int ci = 0; ci < 8; ++ci) {
#pragma unroll
      for (int dy = 0; dy < 3; ++dy) {
        float iv[6];
#pragma unroll
        for (int q = 0; q < 6; ++q)
          iv[q] = ilds[(ci * 4 + row + dy) * 20 + xs + q];
#pragma unroll
        for (int dx = 0; dx < 3; ++dx) {
          float wv[4];
#pragma unroll
          for (int u = 0; u < 4; ++u)
            wv[u] = wlds[(ci * 9 + dy * 3 + dx) * 132 + cog * 4 + u];
#pragma unroll
          for (int u = 0; u < 4; ++u)
#pragma unroll
            for (int v = 0; v < 4; ++v)
              acc[u][v] += wv[u] * iv[v + dx];
        }
      }
    }
  }
  const int y = y0 + row;
#pragma unroll
  for (int u = 0; u < 4; ++u) {
    int co = co0 + cog * 4 + u;
    float bv = bias[co];
    float* ob = out + ((size_t)b * Cn + co) * HWn + y * Wn;
#pragma unroll
    for (int v = 0; v < 4; ++v) {
      int x = x0 + xs + v;
      if (x < Wn) {
        float r2 = acc[u][v] + bv;
        ob[x] = r2 > 0.f ? r2 : 0.f;
      }
    }
  }
}

// ---------------------------------------------------------------------------
// 1x1 conv 256->18, + bias, * scale -> pts
// grid: (40, 4); block 256 (one pixel per thread)
// ---------------------------------------------------------------------------
__global__ __launch_bounds__(256) void offset1x1_kernel(
    const float* __restrict__ t, const float* __restrict__ wo,
    const float* __restrict__ bo, const float* __restrict__ scale_p,
    float* __restrict__ pts)
{
  __shared__ float wl[Cn * 18];   // transposed: wl[c][j]
  for (int i = threadIdx.x; i < 18 * Cn; i += 256) {
    int j = i / Cn, c = i - j * Cn;
    wl[c * 18 + j] = wo[i];
  }
  __syncthreads();
  const int p = blockIdx.x * 256 + threadIdx.x;
  const int b = blockIdx.y;
  if (p >= HWn) return;
  float acc[18];
#pragma unroll
  for (int j = 0; j < 18; ++j) acc[j] = bo[j];
  const float* tb = t + (size_t)b * Cn * HWn + p;
  for (int c = 0; c < Cn; ++c) {
    float v = tb[(size_t)c * HWn];
#pragma unroll
    for (int j = 0; j < 18; ++j) acc[j] += wl[c * 18 + j] * v;
  }
  float s = *scale_p;
#pragma unroll
  for (int j = 0; j < 18; ++j)
    pts[((size_t)b * 18 + j) * HWn + p] = s * acc[j];
}

// ---------------------------------------------------------------------------
// Deformable 1xK conv + relu.  Block: 128 out-ch x 32 pixels.
// grid: (313 ptiles, 2 o-tiles, 4 b); block 256
// wt layout: [k][c][o]
// ---------------------------------------------------------------------------
__global__ __launch_bounds__(256) void deform_conv_kernel(
    const float* __restrict__ feat, const float* __restrict__ wt,
    const float* __restrict__ pts, float* __restrict__ out)
{
  const int p0  = blockIdx.x * 32;
  const int o0  = blockIdx.y * 128;
  const int b   = blockIdx.z;
  const int tid = threadIdx.x;

  __shared__ float wl[32 * 128];    // [ci][o]
  __shared__ float sl[32 * 36];     // [ci][p pad36]
  __shared__ int   ci4[4][32];      // corner indices per pixel (current k)
  __shared__ float cw4[4][32];      // corner weights per pixel (current k)

  const int og  = tid >> 3;         // 0..31 -> o = o0 + og*4 + u
  const int pg  = tid & 7;          //        p = p0 + pg*4 + v
  const int sp  = tid & 31;         // sampling pixel
  const int scb = tid >> 5;         // sampling ci base 0..7

  float acc[4][4] = {};

  const float* fb = feat + (size_t)b * Cn * HWn;
  const float* pb = pts + (size_t)b * 18 * HWn;

  for (int k = 0; k < Kn; ++k) {
    __syncthreads();
    if (tid < 32) {
      int p = p0 + tid;
      float w00 = 0, w01 = 0, w10 = 0, w11 = 0;
      int i00 = 0, i01 = 0, i10 = 0, i11 = 0;
      if (p < HWn) {
        int hy = p / Wn, wx0 = p - hy * Wn;
        float py = pb[(size_t)(2 * k) * HWn + p];
        float px = pb[(size_t)(2 * k + 1) * HWn + p];
        // mirror reference: off = pts - base; ys = h + off_y; xs = w + (k-4) + off_x
        float offx = px - (float)(k - 4);
        float ys  = (float)hy + py;
        float xsf = (float)(wx0 + (k - 4)) + offx;
        float y0f = floorf(ys), x0f = floorf(xsf);
        float wy = ys - y0f, wx = xsf - x0f;
        int y0 = (int)y0f, x0 = (int)x0f;
        int y1 = y0 + 1, x1 = x0 + 1;
        bool vy0 = (unsigned)y0 < (unsigned)Hn, vy1 = (unsigned)y1 < (unsigned)Hn;
        bool vx0 = (unsigned)x0 < (unsigned)Wn, vx1 = (unsigned)x1 < (unsigned)Wn;
        int yc0 = min(max(y0, 0), Hn - 1), yc1 = min(max(y1, 0), Hn - 1);
        int xc0 = min(max(x0, 0), Wn - 1), xc1 = min(max(x1, 0), Wn - 1);
        i00 = yc0 * Wn + xc0; i01 = yc0 * Wn + xc1;
        i10 = yc1 * Wn + xc0; i11 = yc1 * Wn + xc1;
        float oy = 1.f - wy, ox = 1.f - wx;
        w00 = (vy0 && vx0) ? oy * ox : 0.f;
        w01 = (vy0 && vx1) ? oy * wx : 0.f;
        w10 = (vy1 && vx0) ? wy * ox : 0.f;
        w11 = (vy1 && vx1) ? wy * wx : 0.f;
      }
      ci4[0][tid] = i00; ci4[1][tid] = i01; ci4[2][tid] = i10; ci4[3][tid] = i11;
      cw4[0][tid] = w00; cw4[1][tid] = w01; cw4[2][tid] = w10; cw4[3][tid] = w11;
    }
    const float* wk = wt + (size_t)k * Cn * Cn;
    for (int c0 = 0; c0 < Cn; c0 += 32) {
      __syncthreads();
      // weight chunk [32 ci][128 o], coalesced
      for (int i = tid; i < 32 * 128; i += 256) {
        int ci = i >> 7;
        int o  = i & 127;
        wl[i] = wk[(size_t)(c0 + ci) * Cn + o0 + o];
      }
      // bilinear sampling: 4 samples/thread -> sl[ci][p]
      {
        int   j00 = ci4[0][sp], j01 = ci4[1][sp], j10 = ci4[2][sp], j11 = ci4[3][sp];
        float u00 = cw4[0][sp], u01 = cw4[1][sp], u10 = cw4[2][sp], u11 = cw4[3][sp];
#pragma unroll
        for (int j = 0; j < 4; ++j) {
          int ci = scb + j * 8;
          const float* f = fb + (size_t)(c0 + ci) * HWn;
          float v = u00 * f[j00] + u01 * f[j01] + u10 * f[j10] + u11 * f[j11];
          sl[ci * 36 + sp] = v;
        }
      }
      __syncthreads();
#pragma unroll
      for (int ci = 0; ci < 32; ++ci) {
        float wv[4], sv[4];
#pragma unroll
        for (int u = 0; u < 4; ++u) wv[u] = wl[ci * 128 + og * 4 + u];
#pragma unroll
        for (int v = 0; v < 4; ++v) sv[v] = sl[ci * 36 + pg * 4 + v];
#pragma unroll
        for (int u = 0; u < 4; ++u)
#pragma unroll
          for (int v = 0; v < 4; ++v)
            acc[u][v] += wv[u] * sv[v];
      }
    }
  }
#pragma unroll
  for (int u = 0; u < 4; ++u) {
    int o = o0 + og * 4 + u;
    float* ob = out + ((size_t)b * Cn + o) * HWn;
#pragma unroll
    for (int v = 0; v < 4; ++v) {
      int p = p0 + pg * 4 + v;
      if (p < HWn) {
        float r2 = acc[u][v];
        ob[p] = r2 > 0.f ? r2 : 0.f;
      }
    }
  }
}

// ---------------------------------------------------------------------------
extern "C" void kernel_launch(void* const* d_in, const int* in_sizes, int n_in,
                              void* d_out, int out_size, void* d_ws, size_t ws_size,
                              hipStream_t stream) {
  const float* cls_feat = (const float*)d_in[0];
  const float* reg_feat = (const float*)d_in[1];
  const float* scale    = (const float*)d_in[2];
  const float* ocw      = (const float*)d_in[3];
  const float* ocb      = (const float*)d_in[4];
  const float* oow      = (const float*)d_in[5];
  const float* oob      = (const float*)d_in[6];
  const float* wcls     = (const float*)d_in[7];
  const float* wreg     = (const float*)d_in[8];

  float* out_cls = (float*)d_out;                       // [4,256,100,100]
  float* out_reg = out_cls + (size_t)Bn * Cn * HWn;     // [4,256,100,100]
  float* pts     = out_reg + (size_t)Bn * Cn * HWn;     // [4,18,100,100]

  float* t  = (float*)d_ws;                             // [4,256,100,100] = 40.96 MB
  float* wt = t + (size_t)Bn * Cn * HWn;                // [2,9,256,256]   = 4.7 MB

  wtrans_kernel<<<dim3(512), 256, 0, stream>>>(wcls, wreg, wt);
  conv3x3_relu_kernel<<<dim3(350, 2, 4), 256, 0, stream>>>(reg_feat, ocw, ocb, t);
  offset1x1_kernel<<<dim3(40, 4), 256, 0, stream>>>(t, oow, oob, scale, pts);
  deform_conv_kernel<<<dim3(313, 2, 4), 256, 0, stream>>>(
      cls_feat, wt, pts, out_cls);
  deform_conv_kernel<<<dim3(313, 2, 4), 256, 0, stream>>>(
      reg_feat, wt + (size_t)Kn * Cn * Cn, pts, out_reg);
}

// Round 2
// 1385.796 us; speedup vs baseline: 2.1570x; 2.1570x over previous
//
#include <hip/hip_runtime.h>
#include <cstddef>

#define Bn 4
#define Cn 256
#define Hn 100
#define Wn 100
#define HWn 10000
#define Kn 9

typedef __attribute__((ext_vector_type(8))) short short8v;   // 8 bf16
typedef __attribute__((ext_vector_type(4))) float floatx4;
typedef __attribute__((ext_vector_type(4))) unsigned short ushort4v;

__device__ __forceinline__ float b2f(short s) {
  return __uint_as_float(((unsigned)(unsigned short)s) << 16);
}
__device__ __forceinline__ unsigned short f2bf(float f) {
  unsigned u = __float_as_uint(f);
  unsigned r = (u + 0x7FFF + ((u >> 16) & 1)) >> 16;   // RNE
  return (unsigned short)r;
}
__device__ __forceinline__ void gload_lds16(const ushort* g, ushort* l) {
  __builtin_amdgcn_global_load_lds(
      (const __attribute__((address_space(1))) unsigned int*)(g),
      (__attribute__((address_space(3))) unsigned int*)(l), 16, 0, 0);
}

// ---------------------------------------------------------------------------
// Frag-ready bf16 weights: wtA[(br*9+k)*8+cc][ot(16)][lane(64)][j(8)]
// element = w[o = ot*16+(lane&15)][c = cc*32+(lane>>4)*8+j][k]
// grid: 144 blocks x 256
// ---------------------------------------------------------------------------
__global__ __launch_bounds__(256) void wtA_kernel(
    const float* __restrict__ wcls, const float* __restrict__ wreg,
    ushort* __restrict__ wtA)
{
  int bk = blockIdx.x;                 // (br*9 + k)*8 + cc
  int cc = bk & 7;
  int kk = (bk >> 3) % 9;
  int br = bk / 72;
  const float* w = br ? wreg : wcls;
  ushort* dst = wtA + (size_t)bk * 8192;
  for (int idx = threadIdx.x; idx < 8192; idx += 256) {
    int ot = idx >> 9;
    int l  = (idx >> 3) & 63;
    int j  = idx & 7;
    int o  = ot * 16 + (l & 15);
    int c  = cc * 32 + ((l >> 4) << 3) + j;
    dst[idx] = f2bf(w[((size_t)o * Cn + c) * Kn + kk]);
  }
}

// ---------------------------------------------------------------------------
// Transpose+convert feats: ft[(br*4+b)][p][c] bf16 from [b][c][p] fp32
// grid: (313 ptiles, 8 ctiles, 8 z=br*4+b); block 256
// ---------------------------------------------------------------------------
__global__ __launch_bounds__(256) void ftrans_kernel(
    const float* __restrict__ clsf, const float* __restrict__ regf,
    ushort* __restrict__ ft)
{
  const int p0 = blockIdx.x * 32;
  const int c0 = blockIdx.y * 32;
  const int z  = blockIdx.z;
  const int br = z >> 2, b = z & 3;
  const float* src = (br ? regf : clsf) + (size_t)b * Cn * HWn;
  __shared__ float tl[32][33];
  const int tid = threadIdx.x;
  for (int i = tid; i < 1024; i += 256) {
    int c = i >> 5, p = i & 31;
    int pp = p0 + p;
    tl[p][c] = (pp < HWn) ? src[(size_t)(c0 + c) * HWn + pp] : 0.f;
  }
  __syncthreads();
  int p = tid >> 3;
  int c = (tid & 7) * 4;
  int pp = p0 + p;
  if (pp < HWn) {
    ushort4v v;
    v.x = f2bf(tl[p][c + 0]);
    v.y = f2bf(tl[p][c + 1]);
    v.z = f2bf(tl[p][c + 2]);
    v.w = f2bf(tl[p][c + 3]);
    *(ushort4v*)(ft + ((size_t)z * HWn + pp) * Cn + c0 + c) = v;
  }
}

// ---------------------------------------------------------------------------
// conv3x3 (pad 1) + bias + relu (fp32, unchanged from round 0)
// ---------------------------------------------------------------------------
__global__ __launch_bounds__(256) void conv3x3_relu_kernel(
    const float* __restrict__ in, const float* __restrict__ w,
    const float* __restrict__ bias, float* __restrict__ out)
{
  const int xt  = blockIdx.x % 7;
  const int yt  = blockIdx.x / 7;
  const int co0 = blockIdx.y * 128;
  const int b   = blockIdx.z;
  const int x0  = xt * 16;
  const int y0  = yt * 2;
  const int tid = threadIdx.x;
  const int cog = tid >> 3;
  const int xg  = tid & 7;
  const int row = xg >> 2;
  const int xs  = (xg & 3) * 4;

  __shared__ float wlds[8 * 9 * 132];
  __shared__ float ilds[8 * 4 * 20];

  float acc[4][4] = {};
  const float* inb = in + (size_t)b * Cn * HWn;

  for (int ci0 = 0; ci0 < Cn; ci0 += 8) {
    __syncthreads();
    for (int i = tid; i < 128 * 72; i += 256) {
      int co = i / 72, j = i % 72;
      int ci = j / 9, tap = j % 9;
      wlds[(ci * 9 + tap) * 132 + co] =
          w[(size_t)(co0 + co) * (Cn * 9) + (size_t)ci0 * 9 + j];
    }
    for (int i = tid; i < 8 * 4 * 18; i += 256) {
      int ci = i / 72, r = i % 72;
      int rr = r / 18, xx = r % 18;
      int yy = y0 + rr - 1;
      int xi = x0 + xx - 1;
      float v = 0.f;
      if (yy >= 0 && yy < Hn && xi >= 0 && xi < Wn)
        v = inb[(size_t)(ci0 + ci) * HWn + yy * Wn + xi];
      ilds[(ci * 4 + rr) * 20 + xx] = v;
    }
    __syncthreads();
#pragma unroll
    for (int ci = 0; ci < 8; ++ci) {
#pragma unroll
      for (int dy = 0; dy < 3; ++dy) {
        float iv[6];
#pragma unroll
        for (int q = 0; q < 6; ++q)
          iv[q] = ilds[(ci * 4 + row + dy) * 20 + xs + q];
#pragma unroll
        for (int dx = 0; dx < 3; ++dx) {
          float wv[4];
#pragma unroll
          for (int u = 0; u < 4; ++u)
            wv[u] = wlds[(ci * 9 + dy * 3 + dx) * 132 + cog * 4 + u];
#pragma unroll
          for (int u = 0; u < 4; ++u)
#pragma unroll
            for (int v = 0; v < 4; ++v)
              acc[u][v] += wv[u] * iv[v + dx];
        }
      }
    }
  }
  const int y = y0 + row;
#pragma unroll
  for (int u = 0; u < 4; ++u) {
    int co = co0 + cog * 4 + u;
    float bv = bias[co];
    float* ob = out + ((size_t)b * Cn + co) * HWn + y * Wn;
#pragma unroll
    for (int v = 0; v < 4; ++v) {
      int x = x0 + xs + v;
      if (x < Wn) {
        float r2 = acc[u][v] + bv;
        ob[x] = r2 > 0.f ? r2 : 0.f;
      }
    }
  }
}

// ---------------------------------------------------------------------------
// 1x1 conv 256->18, + bias, * scale -> pts (unchanged)
// ---------------------------------------------------------------------------
__global__ __launch_bounds__(256) void offset1x1_kernel(
    const float* __restrict__ t, const float* __restrict__ wo,
    const float* __restrict__ bo, const float* __restrict__ scale_p,
    float* __restrict__ pts)
{
  __shared__ float wl[Cn * 18];
  for (int i = threadIdx.x; i < 18 * Cn; i += 256) {
    int j = i / Cn, c = i - j * Cn;
    wl[c * 18 + j] = wo[i];
  }
  __syncthreads();
  const int p = blockIdx.x * 256 + threadIdx.x;
  const int b = blockIdx.y;
  if (p >= HWn) return;
  float acc[18];
#pragma unroll
  for (int j = 0; j < 18; ++j) acc[j] = bo[j];
  const float* tb = t + (size_t)b * Cn * HWn + p;
  for (int c = 0; c < Cn; ++c) {
    float v = tb[(size_t)c * HWn];
#pragma unroll
    for (int j = 0; j < 18; ++j) acc[j] += wl[c * 18 + j] * v;
  }
  float s = *scale_p;
#pragma unroll
  for (int j = 0; j < 18; ++j)
    pts[((size_t)b * 18 + j) * HWn + p] = s * acc[j];
}

// ---------------------------------------------------------------------------
// Deformable 1xK conv + relu via bf16 MFMA, both branches fused.
// Block: 256 thr = 4 waves. Tile: M=256 out-ch x N=64 px. K = 9k x 8 cc x 32.
// grid: (157, 1, 8=br*4+b)
// ---------------------------------------------------------------------------
__global__ __launch_bounds__(256) void deform_mfma_kernel(
    const ushort* __restrict__ ft, const ushort* __restrict__ wtA,
    const float* __restrict__ pts, float* __restrict__ out)
{
  const int p0  = blockIdx.x * 64;
  const int z   = blockIdx.z;
  const int br  = z >> 2, b = z & 3;
  const int tid = threadIdx.x;
  const int wv  = tid >> 6;
  const int lane = tid & 63;

  __shared__ ushort al[8192];   // A chunk [ot16][lane64][j8] = 16 KB
  __shared__ ushort sl[2048];   // B chunk [pt4][slot64][j8]  = 4 KB

  floatx4 acc[4][4]{};

  const ushort* ftb = ft + (size_t)z * HWn * Cn;
  const float*  pb  = pts + (size_t)b * 18 * HWn;
  const ushort* wA  = wtA + (size_t)br * 9 * 8 * 8192;

  const int px = p0 + lane;           // this lane's sampling pixel
  const bool pvalid = px < HWn;
  const int pxc = pvalid ? px : 0;
  const int hy  = pxc / Wn;
  const int wx0 = pxc - hy * Wn;
  // B-frag LDS slot for this thread's 8 samples (pixel px, ck = wv*8+jj)
  const int sidx = (((lane >> 4) * 64) + (lane & 15) + (wv << 4)) * 8;

  for (int k = 0; k < Kn; ++k) {
    // ---- bilinear corner data for (px, k), per lane (redundant per wave)
    float w00 = 0, w01 = 0, w10 = 0, w11 = 0;
    int i00 = 0, i01 = 0, i10 = 0, i11 = 0;
    {
      float py  = pb[(size_t)(2 * k) * HWn + pxc];
      float pxo = pb[(size_t)(2 * k + 1) * HWn + pxc];
      // mirror reference arithmetic exactly:
      float offx = pxo - (float)(k - 4);
      float ys   = (float)hy + py;
      float xsf  = (float)(wx0 + (k - 4)) + offx;
      float y0f = floorf(ys), x0f = floorf(xsf);
      float wy = ys - y0f, wx = xsf - x0f;
      int y0 = (int)y0f, x0 = (int)x0f;
      int y1 = y0 + 1, x1 = x0 + 1;
      bool vy0 = (unsigned)y0 < (unsigned)Hn, vy1 = (unsigned)y1 < (unsigned)Hn;
      bool vx0 = (unsigned)x0 < (unsigned)Wn, vx1 = (unsigned)x1 < (unsigned)Wn;
      int yc0 = min(max(y0, 0), Hn - 1), yc1 = min(max(y1, 0), Hn - 1);
      int xc0 = min(max(x0, 0), Wn - 1), xc1 = min(max(x1, 0), Wn - 1);
      i00 = (yc0 * Wn + xc0) * Cn; i01 = (yc0 * Wn + xc1) * Cn;
      i10 = (yc1 * Wn + xc0) * Cn; i11 = (yc1 * Wn + xc1) * Cn;
      float oy = 1.f - wy, ox = 1.f - wx;
      bool pv = pvalid;
      w00 = (pv && vy0 && vx0) ? oy * ox : 0.f;
      w01 = (pv && vy0 && vx1) ? oy * wx : 0.f;
      w10 = (pv && vy1 && vx0) ? wy * ox : 0.f;
      w11 = (pv && vy1 && vx1) ? wy * wx : 0.f;
    }

    for (int cc = 0; cc < 8; ++cc) {
      __syncthreads();   // previous MFMA reads done before overwrite
      // ---- stage A chunk (16 KB, linear) via global_load_lds
      {
        const ushort* src = wA + (((size_t)k * 8 + cc) << 13) + tid * 8;
#pragma unroll
        for (int i = 0; i < 4; ++i)
          gload_lds16(src + i * 2048, al + tid * 8 + i * 2048);
      }
      // ---- sample B chunk: 8 channels for pixel px -> frag-ready LDS
      {
        const ushort* fbase = ftb + cc * 32 + (wv << 3);
        short8v c00 = *(const short8v*)(fbase + i00);
        short8v c01 = *(const short8v*)(fbase + i01);
        short8v c10 = *(const short8v*)(fbase + i10);
        short8v c11 = *(const short8v*)(fbase + i11);
        short8v r;
#pragma unroll
        for (int jj = 0; jj < 8; ++jj) {
          float v = w00 * b2f(c00[jj]) + w01 * b2f(c01[jj])
                  + w10 * b2f(c10[jj]) + w11 * b2f(c11[jj]);
          r[jj] = (short)f2bf(v);
        }
        *(short8v*)(sl + sidx) = r;
      }
      __syncthreads();   // drains global_load_lds (vmcnt) + ds_write (lgkm)
      // ---- MFMA: wave wv owns out rows [wv*64, wv*64+64)
      short8v fb[4];
#pragma unroll
      for (int nt = 0; nt < 4; ++nt)
        fb[nt] = *(const short8v*)(sl + (nt * 64 + lane) * 8);
#pragma unroll
      for (int mt = 0; mt < 4; ++mt) {
        short8v fa = *(const short8v*)(al + (((wv * 4 + mt) * 64) + lane) * 8);
#pragma unroll
        for (int nt = 0; nt < 4; ++nt)
          acc[mt][nt] = __builtin_amdgcn_mfma_f32_16x16x32_bf16(
              fa, fb[nt], acc[mt][nt], 0, 0, 0);
      }
    }
  }

  // ---- epilogue: D col = lane&15 (px), row = (lane>>4)*4 + reg (o)
  float* ob = out + (size_t)br * Bn * Cn * HWn + (size_t)b * Cn * HWn;
#pragma unroll
  for (int mt = 0; mt < 4; ++mt) {
    int o = wv * 64 + mt * 16 + ((lane >> 4) << 2);
#pragma unroll
    for (int nt = 0; nt < 4; ++nt) {
      int p = p0 + nt * 16 + (lane & 15);
      if (p < HWn) {
        floatx4 a4 = acc[mt][nt];
#pragma unroll
        for (int r = 0; r < 4; ++r) {
          float v = a4[r];
          ob[(size_t)(o + r) * HWn + p] = v > 0.f ? v : 0.f;
        }
      }
    }
  }
}

// ---------------------------------------------------------------------------
extern "C" void kernel_launch(void* const* d_in, const int* in_sizes, int n_in,
                              void* d_out, int out_size, void* d_ws, size_t ws_size,
                              hipStream_t stream) {
  const float* cls_feat = (const float*)d_in[0];
  const float* reg_feat = (const float*)d_in[1];
  const float* scale    = (const float*)d_in[2];
  const float* ocw      = (const float*)d_in[3];
  const float* ocb      = (const float*)d_in[4];
  const float* oow      = (const float*)d_in[5];
  const float* oob      = (const float*)d_in[6];

  float* out_all = (float*)d_out;                      // cls | reg | pts
  float* pts     = out_all + (size_t)2 * Bn * Cn * HWn;

  // ws: [ t (fp32, 40.96MB) -> reused as ft (bf16, 40.96MB) ][ wtA 2.36MB ]
  float*  t   = (float*)d_ws;
  ushort* ft  = (ushort*)d_ws;
  ushort* wtA = (ushort*)((char*)d_ws + (size_t)Bn * Cn * HWn * 4);

  wtA_kernel<<<dim3(144), 256, 0, stream>>>(
      (const float*)d_in[7], (const float*)d_in[8], wtA);
  conv3x3_relu_kernel<<<dim3(350, 2, 4), 256, 0, stream>>>(reg_feat, ocw, ocb, t);
  offset1x1_kernel<<<dim3(40, 4), 256, 0, stream>>>(t, oow, oob, scale, pts);
  // t is dead now; ft overwrites its region
  ftrans_kernel<<<dim3(313, 8, 8), 256, 0, stream>>>(cls_feat, reg_feat, ft);
  deform_mfma_kernel<<<dim3(157, 1, 8), 256, 0, stream>>>(ft, wtA, pts, out_all);
}

// Round 3
// 591.540 us; speedup vs baseline: 5.0532x; 2.3427x over previous
//
#include <hip/hip_runtime.h>
#include <cstddef>

#define Bn 4
#define Cn 256
#define Hn 100
#define Wn 100
#define HWn 10000
#define Kn 9

typedef __attribute__((ext_vector_type(8))) short short8v;   // 8 bf16
typedef __attribute__((ext_vector_type(4))) float floatx4;
typedef __attribute__((ext_vector_type(4))) unsigned short ushort4v;

__device__ __forceinline__ float b2f(short s) {
  return __uint_as_float(((unsigned)(unsigned short)s) << 16);
}
__device__ __forceinline__ unsigned short f2bf(float f) {
  unsigned u = __float_as_uint(f);
  unsigned r = (u + 0x7FFF + ((u >> 16) & 1)) >> 16;   // RNE
  return (unsigned short)r;
}
__device__ __forceinline__ void gload_lds16(const ushort* g, ushort* l) {
  __builtin_amdgcn_global_load_lds(
      (const __attribute__((address_space(1))) unsigned int*)(g),
      (__attribute__((address_space(3))) unsigned int*)(l), 16, 0, 0);
}

// ---------------------------------------------------------------------------
// Frag-ready bf16 weights for all three [256][256][9] weight tensors:
//   wtAll[(br*9+k)*8+cc][ot(16)][lane(64)][j(8)]
//   element = w_br[o = ot*16+(lane&15)][c = cc*32+(lane>>4)*8+j][k]
// br: 0=cls_dcn, 1=reg_dcn, 2=offset_conv3x3.  grid: 216 blocks x 256
// ---------------------------------------------------------------------------
__global__ __launch_bounds__(256) void wtAll_kernel(
    const float* __restrict__ wcls, const float* __restrict__ wreg,
    const float* __restrict__ wconv, ushort* __restrict__ wtAll)
{
  int bk = blockIdx.x;                 // (br*9 + k)*8 + cc
  int cc = bk & 7;
  int kk = (bk >> 3) % 9;
  int br = bk / 72;
  const float* w = (br == 0) ? wcls : (br == 1) ? wreg : wconv;
  ushort* dst = wtAll + (size_t)bk * 8192;
  for (int idx = threadIdx.x; idx < 8192; idx += 256) {
    int ot = idx >> 9;
    int l  = (idx >> 3) & 63;
    int j  = idx & 7;
    int o  = ot * 16 + (l & 15);
    int c  = cc * 32 + ((l >> 4) << 3) + j;
    dst[idx] = f2bf(w[((size_t)o * Cn + c) * Kn + kk]);
  }
}

// ---------------------------------------------------------------------------
// Transpose+convert feats: ft[(br*4+b)][p][c] bf16 from [b][c][p] fp32
// grid: (313 ptiles, 8 ctiles, 8 z=br*4+b); block 256
// ---------------------------------------------------------------------------
__global__ __launch_bounds__(256) void ftrans_kernel(
    const float* __restrict__ clsf, const float* __restrict__ regf,
    ushort* __restrict__ ft)
{
  const int p0 = blockIdx.x * 32;
  const int c0 = blockIdx.y * 32;
  const int z  = blockIdx.z;
  const int br = z >> 2, b = z & 3;
  const float* src = (br ? regf : clsf) + (size_t)b * Cn * HWn;
  __shared__ float tl[32][33];
  const int tid = threadIdx.x;
  for (int i = tid; i < 1024; i += 256) {
    int c = i >> 5, p = i & 31;
    int pp = p0 + p;
    tl[p][c] = (pp < HWn) ? src[(size_t)(c0 + c) * HWn + pp] : 0.f;
  }
  __syncthreads();
  int p = tid >> 3;
  int c = (tid & 7) * 4;
  int pp = p0 + p;
  if (pp < HWn) {
    ushort4v v;
    v.x = f2bf(tl[p][c + 0]);
    v.y = f2bf(tl[p][c + 1]);
    v.z = f2bf(tl[p][c + 2]);
    v.w = f2bf(tl[p][c + 3]);
    *(ushort4v*)(ft + ((size_t)z * HWn + pp) * Cn + c0 + c) = v;
  }
}

// ---------------------------------------------------------------------------
// conv3x3(pad1)+bias+relu as 9 shifted 1x1 MFMA GEMMs, fused with the
// 1x1 offset conv (256->18, +bias, *scale) -> writes pts directly.
// Block: 256 thr = 4 waves; tile M=256 co x N=64 px; K = 9 taps x 8 cc x 32.
// grid: (157, 1, 4 b)
// ---------------------------------------------------------------------------
__global__ __launch_bounds__(256) void conv3x3_offset_kernel(
    const ushort* __restrict__ ft, const ushort* __restrict__ wtC,
    const float* __restrict__ ocb, const float* __restrict__ oow,
    const float* __restrict__ oob, const float* __restrict__ scale_p,
    float* __restrict__ pts)
{
  const int p0  = blockIdx.x * 64;
  const int b   = blockIdx.z;
  const int tid = threadIdx.x;
  const int wv  = tid >> 6;
  const int lane = tid & 63;

  __shared__ ushort al[8192];        // A chunk (weights)        16 KB
  __shared__ ushort sl[2048];        // B chunk (shifted pixels)  4 KB
  __shared__ ushort tl[Cn * 64];     // relu(t) tile [c][p] bf16 32 KB

  floatx4 acc[4][4]{};

  const ushort* ftb = ft + (size_t)(4 + b) * HWn * Cn;   // reg branch, bf16

  const int px = p0 + lane;
  const bool pvalid = px < HWn;
  const int pxc = pvalid ? px : 0;
  const int y  = pxc / Wn;
  const int x  = pxc - y * Wn;
  const int sidx = (((lane >> 4) * 64) + (lane & 15) + (wv << 4)) * 8;

  for (int tap = 0; tap < 9; ++tap) {
    const int dy = tap / 3 - 1, dx = tap % 3 - 1;
    const int yy = y + dy, xx = x + dx;
    const bool valid = pvalid && (unsigned)yy < (unsigned)Hn
                              && (unsigned)xx < (unsigned)Wn;
    const int pofs = valid ? (yy * Wn + xx) * Cn : 0;

    for (int cc = 0; cc < 8; ++cc) {
      __syncthreads();
      {
        const ushort* src = wtC + (((size_t)tap * 8 + cc) << 13) + tid * 8;
#pragma unroll
        for (int i = 0; i < 4; ++i)
          gload_lds16(src + i * 2048, al + tid * 8 + i * 2048);
      }
      {
        short8v v{};
        if (valid) v = *(const short8v*)(ftb + pofs + cc * 32 + (wv << 3));
        *(short8v*)(sl + sidx) = v;
      }
      __syncthreads();
      short8v fb[4];
#pragma unroll
      for (int nt = 0; nt < 4; ++nt)
        fb[nt] = *(const short8v*)(sl + (nt * 64 + lane) * 8);
#pragma unroll
      for (int mt = 0; mt < 4; ++mt) {
        short8v fa = *(const short8v*)(al + (((wv * 4 + mt) * 64) + lane) * 8);
#pragma unroll
        for (int nt = 0; nt < 4; ++nt)
          acc[mt][nt] = __builtin_amdgcn_mfma_f32_16x16x32_bf16(
              fa, fb[nt], acc[mt][nt], 0, 0, 0);
      }
    }
  }

  // ---- epilogue 1: bias + relu -> bf16 tile tl[c][p]
#pragma unroll
  for (int mt = 0; mt < 4; ++mt) {
    int o = wv * 64 + mt * 16 + ((lane >> 4) << 2);
#pragma unroll
    for (int nt = 0; nt < 4; ++nt) {
      int pcol = nt * 16 + (lane & 15);
      floatx4 a4 = acc[mt][nt];
#pragma unroll
      for (int r = 0; r < 4; ++r) {
        float v = a4[r] + ocb[o + r];
        v = v > 0.f ? v : 0.f;
        tl[(o + r) * 64 + pcol] = f2bf(v);
      }
    }
  }
  __syncthreads();

  // ---- epilogue 2: pts[j][p] = scale * (oob[j] + sum_c oow[j][c]*t[c][p])
  const int jw = __builtin_amdgcn_readfirstlane(tid >> 6);  // wave-uniform
  const int pp = tid & 63;
  const float s = *scale_p;
  if (p0 + pp < HWn) {
    for (int j = jw; j < 18; j += 4) {
      float a = oob[j];
      const float* wrow = oow + (size_t)j * Cn;
      for (int c = 0; c < Cn; ++c)
        a += wrow[c] * b2f(tl[c * 64 + pp]);
      pts[((size_t)b * 18 + j) * HWn + p0 + pp] = s * a;
    }
  }
}

// ---------------------------------------------------------------------------
// Deformable 1xK conv + relu via bf16 MFMA, both branches fused.
// Block: 256 thr = 4 waves. Tile: M=256 out-ch x N=64 px. K = 9k x 8 cc x 32.
// grid: (157, 1, 8=br*4+b)
// ---------------------------------------------------------------------------
__global__ __launch_bounds__(256) void deform_mfma_kernel(
    const ushort* __restrict__ ft, const ushort* __restrict__ wtA,
    const float* __restrict__ pts, float* __restrict__ out)
{
  const int p0  = blockIdx.x * 64;
  const int z   = blockIdx.z;
  const int br  = z >> 2, b = z & 3;
  const int tid = threadIdx.x;
  const int wv  = tid >> 6;
  const int lane = tid & 63;

  __shared__ ushort al[8192];   // A chunk [ot16][lane64][j8] = 16 KB
  __shared__ ushort sl[2048];   // B chunk [pt4][slot64][j8]  = 4 KB

  floatx4 acc[4][4]{};

  const ushort* ftb = ft + (size_t)z * HWn * Cn;
  const float*  pb  = pts + (size_t)b * 18 * HWn;
  const ushort* wA  = wtA + (size_t)br * 9 * 8 * 8192;

  const int px = p0 + lane;
  const bool pvalid = px < HWn;
  const int pxc = pvalid ? px : 0;
  const int hy  = pxc / Wn;
  const int wx0 = pxc - hy * Wn;
  const int sidx = (((lane >> 4) * 64) + (lane & 15) + (wv << 4)) * 8;

  for (int k = 0; k < Kn; ++k) {
    float w00 = 0, w01 = 0, w10 = 0, w11 = 0;
    int i00 = 0, i01 = 0, i10 = 0, i11 = 0;
    {
      float py  = pb[(size_t)(2 * k) * HWn + pxc];
      float pxo = pb[(size_t)(2 * k + 1) * HWn + pxc];
      float offx = pxo - (float)(k - 4);
      float ys   = (float)hy + py;
      float xsf  = (float)(wx0 + (k - 4)) + offx;
      float y0f = floorf(ys), x0f = floorf(xsf);
      float wy = ys - y0f, wx = xsf - x0f;
      int y0 = (int)y0f, x0 = (int)x0f;
      int y1 = y0 + 1, x1 = x0 + 1;
      bool vy0 = (unsigned)y0 < (unsigned)Hn, vy1 = (unsigned)y1 < (unsigned)Hn;
      bool vx0 = (unsigned)x0 < (unsigned)Wn, vx1 = (unsigned)x1 < (unsigned)Wn;
      int yc0 = min(max(y0, 0), Hn - 1), yc1 = min(max(y1, 0), Hn - 1);
      int xc0 = min(max(x0, 0), Wn - 1), xc1 = min(max(x1, 0), Wn - 1);
      i00 = (yc0 * Wn + xc0) * Cn; i01 = (yc0 * Wn + xc1) * Cn;
      i10 = (yc1 * Wn + xc0) * Cn; i11 = (yc1 * Wn + xc1) * Cn;
      float oy = 1.f - wy, ox = 1.f - wx;
      bool pv = pvalid;
      w00 = (pv && vy0 && vx0) ? oy * ox : 0.f;
      w01 = (pv && vy0 && vx1) ? oy * wx : 0.f;
      w10 = (pv && vy1 && vx0) ? wy * ox : 0.f;
      w11 = (pv && vy1 && vx1) ? wy * wx : 0.f;
    }

    for (int cc = 0; cc < 8; ++cc) {
      __syncthreads();
      {
        const ushort* src = wA + (((size_t)k * 8 + cc) << 13) + tid * 8;
#pragma unroll
        for (int i = 0; i < 4; ++i)
          gload_lds16(src + i * 2048, al + tid * 8 + i * 2048);
      }
      {
        const ushort* fbase = ftb + cc * 32 + (wv << 3);
        short8v c00 = *(const short8v*)(fbase + i00);
        short8v c01 = *(const short8v*)(fbase + i01);
        short8v c10 = *(const short8v*)(fbase + i10);
        short8v c11 = *(const short8v*)(fbase + i11);
        short8v r;
#pragma unroll
        for (int jj = 0; jj < 8; ++jj) {
          float v = w00 * b2f(c00[jj]) + w01 * b2f(c01[jj])
                  + w10 * b2f(c10[jj]) + w11 * b2f(c11[jj]);
          r[jj] = (short)f2bf(v);
        }
        *(short8v*)(sl + sidx) = r;
      }
      __syncthreads();
      short8v fb[4];
#pragma unroll
      for (int nt = 0; nt < 4; ++nt)
        fb[nt] = *(const short8v*)(sl + (nt * 64 + lane) * 8);
#pragma unroll
      for (int mt = 0; mt < 4; ++mt) {
        short8v fa = *(const short8v*)(al + (((wv * 4 + mt) * 64) + lane) * 8);
#pragma unroll
        for (int nt = 0; nt < 4; ++nt)
          acc[mt][nt] = __builtin_amdgcn_mfma_f32_16x16x32_bf16(
              fa, fb[nt], acc[mt][nt], 0, 0, 0);
      }
    }
  }

  float* ob = out + (size_t)br * Bn * Cn * HWn + (size_t)b * Cn * HWn;
#pragma unroll
  for (int mt = 0; mt < 4; ++mt) {
    int o = wv * 64 + mt * 16 + ((lane >> 4) << 2);
#pragma unroll
    for (int nt = 0; nt < 4; ++nt) {
      int p = p0 + nt * 16 + (lane & 15);
      if (p < HWn) {
        floatx4 a4 = acc[mt][nt];
#pragma unroll
        for (int r = 0; r < 4; ++r) {
          float v = a4[r];
          ob[(size_t)(o + r) * HWn + p] = v > 0.f ? v : 0.f;
        }
      }
    }
  }
}

// ---------------------------------------------------------------------------
extern "C" void kernel_launch(void* const* d_in, const int* in_sizes, int n_in,
                              void* d_out, int out_size, void* d_ws, size_t ws_size,
                              hipStream_t stream) {
  const float* cls_feat = (const float*)d_in[0];
  const float* reg_feat = (const float*)d_in[1];
  const float* scale    = (const float*)d_in[2];
  const float* ocw      = (const float*)d_in[3];
  const float* ocb      = (const float*)d_in[4];
  const float* oow      = (const float*)d_in[5];
  const float* oob      = (const float*)d_in[6];
  const float* wcls     = (const float*)d_in[7];
  const float* wreg     = (const float*)d_in[8];

  float* out_all = (float*)d_out;                      // cls | reg | pts
  float* pts     = out_all + (size_t)2 * Bn * Cn * HWn;

  // ws: [ ft bf16 8*10000*256 = 40.96MB ][ wtAll 3*9*8*8192 u16 = 3.54MB ]
  ushort* ft    = (ushort*)d_ws;
  ushort* wtAll = (ushort*)((char*)d_ws + (size_t)8 * HWn * Cn * 2);
  ushort* wtC   = wtAll + (size_t)2 * 9 * 8 * 8192;    // conv3x3 weights

  wtAll_kernel<<<dim3(216), 256, 0, stream>>>(wcls, wreg, ocw, wtAll);
  ftrans_kernel<<<dim3(313, 8, 8), 256, 0, stream>>>(cls_feat, reg_feat, ft);
  conv3x3_offset_kernel<<<dim3(157, 1, 4), 256, 0, stream>>>(
      ft, wtC, ocb, oow, oob, scale, pts);
  deform_mfma_kernel<<<dim3(157, 1, 8), 256, 0, stream>>>(
      ft, wtAll, pts, out_all);
}

// Round 4
// 512.902 us; speedup vs baseline: 5.8279x; 1.1533x over previous
//
#include <hip/hip_runtime.h>
#include <cstddef>

#define Bn 4
#define Cn 256
#define Hn 100
#define Wn 100
#define HWn 10000
#define Kn 9

typedef __attribute__((ext_vector_type(8))) short short8v;   // 8 bf16
typedef __attribute__((ext_vector_type(4))) float floatx4;
typedef __attribute__((ext_vector_type(4))) unsigned short ushort4v;

__device__ __forceinline__ float b2f(short s) {
  return __uint_as_float(((unsigned)(unsigned short)s) << 16);
}
__device__ __forceinline__ unsigned short f2bf(float f) {
  unsigned u = __float_as_uint(f);
  unsigned r = (u + 0x7FFF + ((u >> 16) & 1)) >> 16;   // RNE
  return (unsigned short)r;
}
__device__ __forceinline__ void gload_lds16(const ushort* g, ushort* l) {
  __builtin_amdgcn_global_load_lds(
      (const __attribute__((address_space(1))) unsigned int*)(g),
      (__attribute__((address_space(3))) unsigned int*)(l), 16, 0, 0);
}

// ---------------------------------------------------------------------------
// Frag-ready bf16 weights:
//  blocks 0..215: wtAll[(br*9+k)*8+cc][ot16][lane64][j8], br 0=cls,1=reg,2=conv3x3
//  block 216:     oowA[(cc*2+ot)][lane64][j8] for the 1x1 offset head (pad 18->32)
// ---------------------------------------------------------------------------
__global__ __launch_bounds__(256) void wtAll_kernel(
    const float* __restrict__ wcls, const float* __restrict__ wreg,
    const float* __restrict__ wconv, const float* __restrict__ oow,
    ushort* __restrict__ wtAll, ushort* __restrict__ oowA)
{
  int bk = blockIdx.x;
  if (bk == 216) {
    for (int idx = threadIdx.x; idx < 8192; idx += 256) {
      int j = idx & 7;
      int l = (idx >> 3) & 63;
      int q = idx >> 9;               // cc*2+ot
      int cc = q >> 1, ot = q & 1;
      int o = ot * 16 + (l & 15);
      int c = cc * 32 + ((l >> 4) << 3) + j;
      oowA[idx] = (o < 18) ? f2bf(oow[(size_t)o * Cn + c]) : 0;
    }
    return;
  }
  int cc = bk & 7;
  int kk = (bk >> 3) % 9;
  int br = bk / 72;
  const float* w = (br == 0) ? wcls : (br == 1) ? wreg : wconv;
  ushort* dst = wtAll + (size_t)bk * 8192;
  for (int idx = threadIdx.x; idx < 8192; idx += 256) {
    int ot = idx >> 9;
    int l  = (idx >> 3) & 63;
    int j  = idx & 7;
    int o  = ot * 16 + (l & 15);
    int c  = cc * 32 + ((l >> 4) << 3) + j;
    dst[idx] = f2bf(w[((size_t)o * Cn + c) * Kn + kk]);
  }
}

// ---------------------------------------------------------------------------
// Transpose+convert feats: ft[(br*4+b)][p][c] bf16 from [b][c][p] fp32
// ---------------------------------------------------------------------------
__global__ __launch_bounds__(256) void ftrans_kernel(
    const float* __restrict__ clsf, const float* __restrict__ regf,
    ushort* __restrict__ ft)
{
  const int p0 = blockIdx.x * 32;
  const int c0 = blockIdx.y * 32;
  const int z  = blockIdx.z;
  const int br = z >> 2, b = z & 3;
  const float* src = (br ? regf : clsf) + (size_t)b * Cn * HWn;
  __shared__ float tl[32][33];
  const int tid = threadIdx.x;
  for (int i = tid; i < 1024; i += 256) {
    int c = i >> 5, p = i & 31;
    int pp = p0 + p;
    tl[p][c] = (pp < HWn) ? src[(size_t)(c0 + c) * HWn + pp] : 0.f;
  }
  __syncthreads();
  int p = tid >> 3;
  int c = (tid & 7) * 4;
  int pp = p0 + p;
  if (pp < HWn) {
    ushort4v v;
    v.x = f2bf(tl[p][c + 0]);
    v.y = f2bf(tl[p][c + 1]);
    v.z = f2bf(tl[p][c + 2]);
    v.w = f2bf(tl[p][c + 3]);
    *(ushort4v*)(ft + ((size_t)z * HWn + pp) * Cn + c0 + c) = v;
  }
}

// ---------------------------------------------------------------------------
// conv3x3(pad1)+bias+relu as 9 shifted 1x1 MFMA GEMMs, single-barrier
// double-buffered pipeline; fused 1x1 offset head via a small MFMA GEMM.
// Block 256 thr = 4 waves; M=256 co x N=64 px; 72 chunks of K=32.
// grid: (157, 1, 4 b)
// ---------------------------------------------------------------------------
__global__ __launch_bounds__(256) void conv3x3_offset_kernel(
    const ushort* __restrict__ ft, const ushort* __restrict__ wtC,
    const float* __restrict__ ocb, const ushort* __restrict__ oowA,
    const float* __restrict__ oob, const float* __restrict__ scale_p,
    float* __restrict__ pts)
{
  const int p0  = blockIdx.x * 64;
  const int b   = blockIdx.z;
  const int tid = threadIdx.x;
  const int wv  = tid >> 6;
  const int lane = tid & 63;

  __shared__ ushort smem[20480];           // 40 KB
  ushort* al = smem;                       // [2][8192]
  ushort* sl = smem + 16384;               // [2][2048]

  floatx4 acc[4][4]{};

  const ushort* ftb = ft + (size_t)(4 + b) * HWn * Cn;   // reg branch

  const int px = p0 + lane;
  const bool pvalid = px < HWn;
  const int pxc = pvalid ? px : 0;
  const int y  = pxc / Wn;
  const int x  = pxc - y * Wn;
  const int sidx = (((lane >> 4) * 64) + (lane & 15) + (wv << 4)) * 8;

  // per-tap state
  int pofs = 0; bool valid = false;
  auto tapgeo = [&](int tap) {
    int dy = tap / 3 - 1, dx = tap % 3 - 1;
    int yy = y + dy, xx = x + dx;
    valid = pvalid && (unsigned)yy < (unsigned)Hn && (unsigned)xx < (unsigned)Wn;
    pofs = valid ? (yy * Wn + xx) * Cn : 0;
  };

  // ---- prologue: chunk 0 (tap 0, cc 0)
  short8v cv{};
  tapgeo(0);
  if (valid) cv = *(const short8v*)(ftb + pofs + (wv << 3));
  {
    const ushort* srcw = wtC + tid * 8;
#pragma unroll
    for (int i = 0; i < 4; ++i)
      gload_lds16(srcw + i * 2048, al + tid * 8 + i * 2048);
  }
  *(short8v*)(sl + sidx) = cv;

  for (int t = 0; t < 72; ++t) {
    __syncthreads();
    const int buf = t & 1, nb = buf ^ 1;
    if (t < 71) {
      const int t1 = t + 1, cc1 = t1 & 7;
      if (cc1 == 0) tapgeo(t1 >> 3);
      cv = short8v{};
      if (valid) cv = *(const short8v*)(ftb + pofs + cc1 * 32 + (wv << 3));
      const ushort* srcw = wtC + ((size_t)t1 << 13) + tid * 8;
#pragma unroll
      for (int i = 0; i < 4; ++i)
        gload_lds16(srcw + i * 2048, al + nb * 8192 + tid * 8 + i * 2048);
    }
    short8v fbv[4];
#pragma unroll
    for (int nt = 0; nt < 4; ++nt)
      fbv[nt] = *(const short8v*)(sl + buf * 2048 + (nt * 64 + lane) * 8);
#pragma unroll
    for (int mt = 0; mt < 4; ++mt) {
      short8v fa = *(const short8v*)(al + buf * 8192 + (((wv * 4 + mt) * 64) + lane) * 8);
#pragma unroll
      for (int nt = 0; nt < 4; ++nt)
        acc[mt][nt] = __builtin_amdgcn_mfma_f32_16x16x32_bf16(
            fa, fbv[nt], acc[mt][nt], 0, 0, 0);
    }
    if (t < 71) *(short8v*)(sl + nb * 2048 + sidx) = cv;
  }

  // ---- epilogue 1: bias+relu -> tl[px][o] bf16, padded stride 264
  __syncthreads();
  ushort* tl = smem;                       // [64][264] = 16896 <= 20480
#pragma unroll
  for (int mt = 0; mt < 4; ++mt) {
    int ob = wv * 64 + mt * 16 + ((lane >> 4) << 2);
    floatx4 bv = *(const floatx4*)(ocb + ob);
#pragma unroll
    for (int nt = 0; nt < 4; ++nt) {
      int pxl = nt * 16 + (lane & 15);
      floatx4 a4 = acc[mt][nt];
#pragma unroll
      for (int rp = 0; rp < 4; rp += 2) {
        float v0 = a4[rp]     + bv[rp];     v0 = v0 > 0.f ? v0 : 0.f;
        float v1 = a4[rp + 1] + bv[rp + 1]; v1 = v1 > 0.f ? v1 : 0.f;
        unsigned pk = (unsigned)f2bf(v0) | ((unsigned)f2bf(v1) << 16);
        *(unsigned*)(tl + pxl * 264 + ob + rp) = pk;
      }
    }
  }
  __syncthreads();

  // ---- epilogue 2: pts = scale*(oow . t + oob) via MFMA; wave wv owns px tile wv
  floatx4 ap[2]{};
#pragma unroll
  for (int cc = 0; cc < 8; ++cc) {
    short8v fbp = *(const short8v*)(tl + (wv * 16 + (lane & 15)) * 264
                                    + cc * 32 + ((lane >> 4) << 3));
#pragma unroll
    for (int ot = 0; ot < 2; ++ot) {
      short8v faw = *(const short8v*)(oowA + (((cc * 2 + ot) * 64) + lane) * 8);
      ap[ot] = __builtin_amdgcn_mfma_f32_16x16x32_bf16(faw, fbp, ap[ot], 0, 0, 0);
    }
  }
  const float s = *scale_p;
  const int pp = p0 + wv * 16 + (lane & 15);
#pragma unroll
  for (int ot = 0; ot < 2; ++ot)
#pragma unroll
    for (int r = 0; r < 4; ++r) {
      int j = ot * 16 + ((lane >> 4) << 2) + r;
      if (j < 18 && pp < HWn)
        pts[((size_t)b * 18 + j) * HWn + pp] = s * (ap[ot][r] + oob[j]);
    }
}

// ---------------------------------------------------------------------------
// Deformable 1xK conv + relu, single-barrier double-buffered MFMA pipeline.
// Block 256 thr = 4 waves; M=256 o x N=64 px; 72 chunks of K=32.
// grid: (157, 1, 8 = br*4+b)
// ---------------------------------------------------------------------------
__global__ __launch_bounds__(256) void deform_mfma_kernel(
    const ushort* __restrict__ ft, const ushort* __restrict__ wtA,
    const float* __restrict__ pts, float* __restrict__ out)
{
  const int p0  = blockIdx.x * 64;
  const int z   = blockIdx.z;
  const int br  = z >> 2, b = z & 3;
  const int tid = threadIdx.x;
  const int wv  = tid >> 6;
  const int lane = tid & 63;

  __shared__ ushort smem[20480];           // 40 KB
  ushort* al = smem;                       // [2][8192]
  ushort* sl = smem + 16384;               // [2][2048]

  floatx4 acc[4][4]{};

  const ushort* ftb = ft + (size_t)z * HWn * Cn;
  const float*  pb  = pts + (size_t)b * 18 * HWn;
  const ushort* wA  = wtA + (size_t)br * 9 * 8 * 8192;

  const int px = p0 + lane;
  const bool pvalid = px < HWn;
  const int pxc = pvalid ? px : 0;
  const int hy  = pxc / Wn;
  const int wx0 = pxc - hy * Wn;
  const int sidx = (((lane >> 4) * 64) + (lane & 15) + (wv << 4)) * 8;

  // bilinear state (current k)
  float w00 = 0, w01 = 0, w10 = 0, w11 = 0;
  int i00 = 0, i01 = 0, i10 = 0, i11 = 0;
  auto bilinear = [&](int k, float py, float pxo) {
    float offx = pxo - (float)(k - 4);
    float ys   = (float)hy + py;
    float xsf  = (float)(wx0 + (k - 4)) + offx;
    float y0f = floorf(ys), x0f = floorf(xsf);
    float wy = ys - y0f, wx = xsf - x0f;
    int y0 = (int)y0f, x0 = (int)x0f;
    int y1 = y0 + 1, x1 = x0 + 1;
    bool vy0 = (unsigned)y0 < (unsigned)Hn, vy1 = (unsigned)y1 < (unsigned)Hn;
    bool vx0 = (unsigned)x0 < (unsigned)Wn, vx1 = (unsigned)x1 < (unsigned)Wn;
    int yc0 = min(max(y0, 0), Hn - 1), yc1 = min(max(y1, 0), Hn - 1);
    int xc0 = min(max(x0, 0), Wn - 1), xc1 = min(max(x1, 0), Wn - 1);
    i00 = (yc0 * Wn + xc0) * Cn; i01 = (yc0 * Wn + xc1) * Cn;
    i10 = (yc1 * Wn + xc0) * Cn; i11 = (yc1 * Wn + xc1) * Cn;
    float oy = 1.f - wy, ox = 1.f - wx;
    w00 = (pvalid && vy0 && vx0) ? oy * ox : 0.f;
    w01 = (pvalid && vy0 && vx1) ? oy * wx : 0.f;
    w10 = (pvalid && vy1 && vx0) ? wy * ox : 0.f;
    w11 = (pvalid && vy1 && vx1) ? wy * wx : 0.f;
  };

  // pts pair for next k (prefetched one k ahead; static regs)
  float pyN = pb[pxc];
  float pxN = pb[(size_t)HWn + pxc];

  // ---- prologue: chunk 0 (k=0, cc=0)
  bilinear(0, pyN, pxN);
  pyN = pb[(size_t)2 * HWn + pxc];
  pxN = pb[(size_t)3 * HWn + pxc];
  short8v c00, c01, c10, c11;
  {
    const ushort* fbase = ftb + (wv << 3);
    c00 = *(const short8v*)(fbase + i00);
    c01 = *(const short8v*)(fbase + i01);
    c10 = *(const short8v*)(fbase + i10);
    c11 = *(const short8v*)(fbase + i11);
    const ushort* srcw = wA + tid * 8;
#pragma unroll
    for (int i = 0; i < 4; ++i)
      gload_lds16(srcw + i * 2048, al + tid * 8 + i * 2048);
    short8v r;
#pragma unroll
    for (int jj = 0; jj < 8; ++jj) {
      float v = w00 * b2f(c00[jj]) + w01 * b2f(c01[jj])
              + w10 * b2f(c10[jj]) + w11 * b2f(c11[jj]);
      r[jj] = (short)f2bf(v);
    }
    *(short8v*)(sl + sidx) = r;
  }

  for (int t = 0; t < 72; ++t) {
    __syncthreads();
    const int buf = t & 1, nb = buf ^ 1;
    const bool more = t < 71;
    if (more) {
      const int t1 = t + 1, k1 = t1 >> 3, cc1 = t1 & 7;
      if (cc1 == 0) {
        bilinear(k1, pyN, pxN);
        if (k1 < 8) {
          pyN = pb[(size_t)(2 * k1 + 2) * HWn + pxc];
          pxN = pb[(size_t)(2 * k1 + 3) * HWn + pxc];
        }
      }
      const ushort* fbase = ftb + cc1 * 32 + (wv << 3);
      c00 = *(const short8v*)(fbase + i00);
      c01 = *(const short8v*)(fbase + i01);
      c10 = *(const short8v*)(fbase + i10);
      c11 = *(const short8v*)(fbase + i11);
      const ushort* srcw = wA + ((size_t)t1 << 13) + tid * 8;
#pragma unroll
      for (int i = 0; i < 4; ++i)
        gload_lds16(srcw + i * 2048, al + nb * 8192 + tid * 8 + i * 2048);
    }
    short8v fbv[4];
#pragma unroll
    for (int nt = 0; nt < 4; ++nt)
      fbv[nt] = *(const short8v*)(sl + buf * 2048 + (nt * 64 + lane) * 8);
#pragma unroll
    for (int mt = 0; mt < 4; ++mt) {
      short8v fa = *(const short8v*)(al + buf * 8192 + (((wv * 4 + mt) * 64) + lane) * 8);
#pragma unroll
      for (int nt = 0; nt < 4; ++nt)
        acc[mt][nt] = __builtin_amdgcn_mfma_f32_16x16x32_bf16(
            fa, fbv[nt], acc[mt][nt], 0, 0, 0);
    }
    if (more) {
      short8v r;
#pragma unroll
      for (int jj = 0; jj < 8; ++jj) {
        float v = w00 * b2f(c00[jj]) + w01 * b2f(c01[jj])
                + w10 * b2f(c10[jj]) + w11 * b2f(c11[jj]);
        r[jj] = (short)f2bf(v);
      }
      *(short8v*)(sl + nb * 2048 + sidx) = r;
    }
  }

  float* ob = out + (size_t)br * Bn * Cn * HWn + (size_t)b * Cn * HWn;
#pragma unroll
  for (int mt = 0; mt < 4; ++mt) {
    int o = wv * 64 + mt * 16 + ((lane >> 4) << 2);
#pragma unroll
    for (int nt = 0; nt < 4; ++nt) {
      int p = p0 + nt * 16 + (lane & 15);
      if (p < HWn) {
        floatx4 a4 = acc[mt][nt];
#pragma unroll
        for (int r = 0; r < 4; ++r) {
          float v = a4[r];
          ob[(size_t)(o + r) * HWn + p] = v > 0.f ? v : 0.f;
        }
      }
    }
  }
}

// ---------------------------------------------------------------------------
extern "C" void kernel_launch(void* const* d_in, const int* in_sizes, int n_in,
                              void* d_out, int out_size, void* d_ws, size_t ws_size,
                              hipStream_t stream) {
  const float* cls_feat = (const float*)d_in[0];
  const float* reg_feat = (const float*)d_in[1];
  const float* scale    = (const float*)d_in[2];
  const float* ocw      = (const float*)d_in[3];
  const float* ocb      = (const float*)d_in[4];
  const float* oow      = (const float*)d_in[5];
  const float* oob      = (const float*)d_in[6];
  const float* wcls     = (const float*)d_in[7];
  const float* wreg     = (const float*)d_in[8];

  float* out_all = (float*)d_out;                      // cls | reg | pts
  float* pts     = out_all + (size_t)2 * Bn * Cn * HWn;

  // ws: [ ft bf16 8*10000*256 = 40.96MB ][ wtAll 27*8192*2 ][ oowA 16KB ]
  ushort* ft    = (ushort*)d_ws;
  ushort* wtAll = (ushort*)((char*)d_ws + (size_t)8 * HWn * Cn * 2);
  ushort* wtC   = wtAll + (size_t)2 * 9 * 8 * 8192;    // conv3x3 weights
  ushort* oowA  = wtAll + (size_t)3 * 9 * 8 * 8192;

  wtAll_kernel<<<dim3(217), 256, 0, stream>>>(wcls, wreg, ocw, oow, wtAll, oowA);
  ftrans_kernel<<<dim3(313, 8, 8), 256, 0, stream>>>(cls_feat, reg_feat, ft);
  conv3x3_offset_kernel<<<dim3(157, 1, 4), 256, 0, stream>>>(
      ft, wtC, ocb, oowA, oob, scale, pts);
  deform_mfma_kernel<<<dim3(157, 1, 8), 256, 0, stream>>>(
      ft, wtAll, pts, out_all);
}